// Round 9
// baseline (267.559 us; speedup 1.0000x reference)
//
#include <hip/hip_runtime.h>
#include <hip/hip_bf16.h>
#include <stdint.h>

#define B_ 4
#define S_ 2048
#define H_ 1024
#define NH_ 16
#define HD_ 64

typedef __attribute__((ext_vector_type(8))) short short8;
typedef __attribute__((ext_vector_type(4))) float f32x4;
typedef __attribute__((ext_vector_type(4))) unsigned short ushort4v;

__device__ __forceinline__ unsigned short f2bf(float f) {
  union { float f; unsigned u; } x; x.f = f;
  unsigned r = x.u + 0x7fffu + ((x.u >> 16) & 1u);
  return (unsigned short)(r >> 16);
}

#define ALDS16(g, l) \
  __builtin_amdgcn_global_load_lds((const __attribute__((address_space(1))) void*)(g), \
                                   (__attribute__((address_space(3))) void*)(l), 16, 0, 0)

// ---------------- input fp32 -> bf16 convert ----------------
__global__ __launch_bounds__(256) void cvt_in(
    const float* __restrict__ q, const float* __restrict__ k, const float* __restrict__ v,
    unsigned short* __restrict__ oq, unsigned short* __restrict__ ok2, unsigned short* __restrict__ ov) {
  const int z = blockIdx.z;
  const float* src = z == 0 ? q : (z == 1 ? k : v);
  unsigned short* dst = z == 0 ? oq : (z == 1 ? ok2 : ov);
  const size_t i = ((size_t)blockIdx.x * 256 + threadIdx.x) * 8;
  const f32x4 a = *reinterpret_cast<const f32x4*>(src + i);
  const f32x4 c = *reinterpret_cast<const f32x4*>(src + i + 4);
  short8 o;
#pragma unroll
  for (int j = 0; j < 4; ++j) { o[j] = (short)f2bf(a[j]); o[j + 4] = (short)f2bf(c[j]); }
  *reinterpret_cast<short8*>(dst + i) = o;
}

// ---------------- mask fp32 -> bit pack (bit set = KEEP, i.e. mask==0) ----------------
__global__ __launch_bounds__(256) void packmask(
    const float* __restrict__ mask, unsigned long long* __restrict__ mb) {
  const int w = threadIdx.x >> 6, lane = threadIdx.x & 63;
  const int wbase = (blockIdx.x * 4 + w) * 32;
#pragma unroll 8
  for (int i = 0; i < 32; ++i) {
    const float v = mask[(size_t)(wbase + i) * 64 + lane];
    const unsigned long long bits = __ballot(v == 0.0f);
    if (lane == 0) mb[wbase + i] = bits;
  }
}

// ---------------- weight fp32 -> bf16 transpose (Wt[n][k] = W[k][n]) ----------------
__global__ __launch_bounds__(256) void cvt_w(
    const float* __restrict__ Wq, const float* __restrict__ Wk,
    const float* __restrict__ Wv, const float* __restrict__ Wo,
    unsigned short* __restrict__ wt) {
  __shared__ float tile[64][65];
  const int z = blockIdx.z;
  const float* W = z == 0 ? Wq : (z == 1 ? Wk : (z == 2 ? Wv : Wo));
  unsigned short* out = wt + (size_t)z * H_ * H_;
  const int t = threadIdx.x;
  const int r0 = blockIdx.y * 64, c0 = blockIdx.x * 64;
  const int tr = t >> 4, tc = (t & 15) * 4;
#pragma unroll
  for (int rr = 0; rr < 4; ++rr) {
    const int row = rr * 16 + tr;
    const f32x4 val = *reinterpret_cast<const f32x4*>(W + (size_t)(r0 + row) * H_ + c0 + tc);
#pragma unroll
    for (int j = 0; j < 4; ++j) tile[row][tc + j] = val[j];
  }
  __syncthreads();
#pragma unroll
  for (int rr = 0; rr < 4; ++rr) {
    const int c = rr * 16 + tr;
    ushort4v o;
#pragma unroll
    for (int j = 0; j < 4; ++j) o[j] = f2bf(tile[tc + j][c]);
    *reinterpret_cast<ushort4v*>(out + (size_t)(c0 + c) * H_ + r0 + tc) = o;
  }
}

// ---------------- GEMM: C[M,1024] = (X @ Wt^T + bias) * oscale ----------------
template <int OUTMODE>
__device__ __forceinline__ void gemm_body(
    const unsigned short* __restrict__ X, const unsigned short* __restrict__ Wt,
    const float* __restrict__ bias, float oscale, unsigned short* __restrict__ obf,
    float* __restrict__ of32) {
  __shared__ unsigned short As[128 * 64];
  __shared__ unsigned short Bs[128 * 64];
  const int t = threadIdx.x;
  const int w = t >> 6, l = t & 63;
  const int lr = l & 15, lg = l >> 4;
  const int brow = blockIdx.x * 128, bcol = blockIdx.y * 128;
  const int wr = (w >> 1) * 64, wc = (w & 1) * 64;
  f32x4 acc[4][4] = {};
  const unsigned short* xb = X + (size_t)brow * 1024;
  const unsigned short* wb = Wt + (size_t)bcol * 1024;
  int srow[4], skl[4];
#pragma unroll
  for (int j = 0; j < 4; ++j) {
    const int c = t + j * 256;
    srow[j] = c >> 3;
    skl[j] = ((c & 7) ^ ((c >> 3) & 7)) * 8;
  }
  for (int kt = 0; kt < 1024; kt += 64) {
#pragma unroll
    for (int j = 0; j < 4; ++j) {
      ALDS16(xb + (size_t)srow[j] * 1024 + kt + skl[j], As + (t + j * 256) * 8);
      ALDS16(wb + (size_t)srow[j] * 1024 + kt + skl[j], Bs + (t + j * 256) * 8);
    }
    __syncthreads();
#pragma unroll
    for (int kk = 0; kk < 2; ++kk) {
      short8 af[4], bf[4];
#pragma unroll
      for (int m = 0; m < 4; ++m) {
        const int ra = wr + m * 16 + lr;
        af[m] = *reinterpret_cast<const short8*>(As + ra * 64 + ((kk * 4 + lg) ^ (ra & 7)) * 8);
      }
#pragma unroll
      for (int n = 0; n < 4; ++n) {
        const int rb = wc + n * 16 + lr;
        bf[n] = *reinterpret_cast<const short8*>(Bs + rb * 64 + ((kk * 4 + lg) ^ (rb & 7)) * 8);
      }
#pragma unroll
      for (int m = 0; m < 4; ++m)
#pragma unroll
        for (int n = 0; n < 4; ++n)
          acc[m][n] = __builtin_amdgcn_mfma_f32_16x16x32_bf16(af[m], bf[n], acc[m][n], 0, 0, 0);
    }
    __syncthreads();
  }
#pragma unroll
  for (int m = 0; m < 4; ++m) {
#pragma unroll
    for (int n = 0; n < 4; ++n) {
#pragma unroll
      for (int r = 0; r < 4; ++r) {
        const int gr = brow + wr + m * 16 + lg * 4 + r;
        const int gc = bcol + wc + n * 16 + lr;
        const float val = (acc[m][n][r] + bias[gc]) * oscale;
        if (OUTMODE == 0) {
          const int bb = gr >> 11, ss = gr & 2047, hh = gc >> 6, dd = gc & 63;
          obf[(((size_t)(bb * NH_ + hh)) * S_ + ss) * HD_ + dd] = f2bf(val);
        } else {
          of32[(size_t)gr * H_ + gc] = val;
        }
      }
    }
  }
}

// Q is pre-scaled by 0.125*log2(e) so attention can exp2() the raw MFMA output.
#define QSCL 0.1803368801111244f

__global__ __launch_bounds__(256, 4) void gemm_qkv(
    const unsigned short* __restrict__ xq, const unsigned short* __restrict__ xk,
    const unsigned short* __restrict__ xv, const unsigned short* __restrict__ wt,
    const float* __restrict__ bq, const float* __restrict__ bk, const float* __restrict__ bv,
    unsigned short* __restrict__ qh, unsigned short* __restrict__ kh,
    unsigned short* __restrict__ vh) {
  const int z = blockIdx.z;
  const unsigned short* X = z == 0 ? xq : (z == 1 ? xk : xv);
  const unsigned short* W = wt + (size_t)z * H_ * H_;
  const float* bias = z == 0 ? bq : (z == 1 ? bk : bv);
  unsigned short* out = z == 0 ? qh : (z == 1 ? kh : vh);
  const float scl = z == 0 ? QSCL : 1.0f;
  gemm_body<0>(X, W, bias, scl, out, nullptr);
}

__global__ __launch_bounds__(256, 4) void gemm_out(
    const unsigned short* __restrict__ ao, const unsigned short* __restrict__ wt,
    const float* __restrict__ bo, float* __restrict__ out) {
  gemm_body<1>(ao, wt, bo, 1.0f, nullptr, out);
}

// ---------------- V transpose per head: [bh][S][HD] -> [bh][HD][S] ----------------
__global__ __launch_bounds__(256) void vtrans(
    const unsigned short* __restrict__ vh, unsigned short* __restrict__ vt) {
  __shared__ unsigned short tile[64 * 72];
  const int bh = blockIdx.y;
  const int s0 = blockIdx.x * 64;
  const int t = threadIdx.x;
  const unsigned short* src = vh + (size_t)bh * S_ * HD_ + (size_t)s0 * HD_;
#pragma unroll
  for (int r = 0; r < 2; ++r) {
    const int i = t + r * 256;
    const int row = i >> 3, kc = i & 7;
    const short8 v = *reinterpret_cast<const short8*>(src + row * 64 + kc * 8);
    *reinterpret_cast<short8*>(tile + row * 72 + kc * 8) = v;
  }
  __syncthreads();
  unsigned short* dst = vt + (size_t)bh * HD_ * S_;
#pragma unroll
  for (int r = 0; r < 2; ++r) {
    const int i = t + r * 256;
    const int d = i >> 3, sc = i & 7;
    short8 o;
#pragma unroll
    for (int j = 0; j < 8; ++j) o[j] = (short)tile[(sc * 8 + j) * 72 + d];
    *reinterpret_cast<short8*>(dst + (size_t)d * S_ + s0 + sc * 8) = o;
  }
}

// ---------------- flash attention ----------------
// Triple-buffered K/V (stage t+2 at iter t) with counted s_waitcnt vmcnt(4) +
// raw s_barrier: staging loads never drained to 0 inside the loop (T3/T4).
// vmcnt(4) provably covers stage(t+1): its 4 loads precede stage(t+2)'s 4.
// LDS 56 KB -> 2 blocks/CU; L2 residency scheme unchanged (r7: FETCH 28.7 MB).
__global__ __launch_bounds__(256, 2) void attn_kernel(
    const unsigned short* __restrict__ qh, const unsigned short* __restrict__ kh,
    const unsigned short* __restrict__ vt, const unsigned long long* __restrict__ mb,
    unsigned short* __restrict__ ao) {
  __shared__ unsigned short Ks[3][64 * 64];
  __shared__ unsigned short Vs[3][64 * 64];
  __shared__ unsigned short Ps[4][16 * 64];
  const int t = threadIdx.x, w = t >> 6, l = t & 63;
  const int lr = l & 15, lg = l >> 4;
  const int flat = blockIdx.x;
  const int g = flat >> 9;
  const int x = flat & 511;
  const int bh = g * 32 + (x & 7) * 4 + (x >> 7);
  const int qt = (x >> 3) & 15;
  const int b = bh >> 4, h = bh & 15;
  const unsigned short* qptr = qh + (size_t)bh * S_ * HD_;
  const unsigned short* kptr = kh + (size_t)bh * S_ * HD_;
  const unsigned short* vptr = vt + (size_t)bh * HD_ * S_;
  const unsigned long long* mbase = mb + (size_t)b * S_ * (S_ / 64);
  const int qbase = qt * 128 + w * 32;

  short8 qf[2][2];
#pragma unroll
  for (int qs = 0; qs < 2; ++qs) {
    const unsigned short* qp = qptr + (size_t)(qbase + qs * 16 + lr) * HD_ + lg * 8;
    qf[qs][0] = *reinterpret_cast<const short8*>(qp);
    qf[qs][1] = *reinterpret_cast<const short8*>(qp + 32);
  }
  short8 ones;
#pragma unroll
  for (int jj = 0; jj < 8; ++jj) ones[jj] = (short)0x3F80;

  const int si0 = t, si1 = t + 256;
  const int srow0 = si0 >> 3, sk0 = ((si0 & 7) ^ (srow0 & 7)) * 8;
  const int srow1 = si1 >> 3, sk1 = ((si1 & 7) ^ (srow1 & 7)) * 8;
  const unsigned short* ksrc0 = kptr + (size_t)srow0 * HD_ + sk0;
  const unsigned short* ksrc1 = kptr + (size_t)srow1 * HD_ + sk1;
  const unsigned short* vsrc0 = vptr + (size_t)srow0 * S_ + sk0;
  const unsigned short* vsrc1 = vptr + (size_t)srow1 * S_ + sk1;
  size_t moff[2][4];
#pragma unroll
  for (int qs = 0; qs < 2; ++qs)
#pragma unroll
    for (int r = 0; r < 4; ++r)
      moff[qs][r] = (size_t)(qbase + qs * 16 + lg * 4 + r) * (S_ / 64);

  // prologue: stage tiles 0 and 1 into buffers 0 and 1
  ALDS16(ksrc0, Ks[0] + si0 * 8);
  ALDS16(ksrc1, Ks[0] + si1 * 8);
  ALDS16(vsrc0, Vs[0] + si0 * 8);
  ALDS16(vsrc1, Vs[0] + si1 * 8);
  ALDS16(ksrc0 + (size_t)64 * HD_, Ks[1] + si0 * 8);
  ALDS16(ksrc1 + (size_t)64 * HD_, Ks[1] + si1 * 8);
  ALDS16(vsrc0 + 64, Vs[1] + si0 * 8);
  ALDS16(vsrc1 + 64, Vs[1] + si1 * 8);
  asm volatile("s_waitcnt vmcnt(4)");   // tile 0 landed; tile 1 still in flight
  __builtin_amdgcn_s_barrier();
  __builtin_amdgcn_sched_barrier(0);

  f32x4 acc_o[2][4] = {};
  f32x4 acc_l[2] = {};
  unsigned short* pw = Ps[w];
  int cur = 0;

  for (int kv = 0; kv < S_; kv += 64) {
    unsigned msel[2][4][4];
#pragma unroll
    for (int qs = 0; qs < 2; ++qs)
#pragma unroll
      for (int r = 0; r < 4; ++r) {
        const unsigned long long mwv = mbase[moff[qs][r] + (kv >> 6)];
        const unsigned long long sh = mwv >> lr;
        const unsigned lo = (unsigned)sh, hi = (unsigned)(sh >> 32);
        msel[qs][r][0] = 0u - (lo & 1u);
        msel[qs][r][1] = 0u - ((lo >> 16) & 1u);
        msel[qs][r][2] = 0u - (hi & 1u);
        msel[qs][r][3] = 0u - ((hi >> 16) & 1u);
      }

    // stage tile t+2 into buffer (cur+2)%3
    const int stb = (cur == 0) ? 2 : cur - 1;
    const int nkv = (kv + 128 < S_) ? kv + 128 : kv + 128 - S_;
    ALDS16(ksrc0 + (size_t)nkv * HD_, Ks[stb] + si0 * 8);
    ALDS16(ksrc1 + (size_t)nkv * HD_, Ks[stb] + si1 * 8);
    ALDS16(vsrc0 + nkv, Vs[stb] + si0 * 8);
    ALDS16(vsrc1 + nkv, Vs[stb] + si1 * 8);

    const unsigned short* Kc = Ks[cur];
    const unsigned short* Vc = Vs[cur];

    float p[2][4][4];
#pragma unroll
    for (int n = 0; n < 4; ++n) {
      const int krow = n * 16 + lr;
      const short8 kf0 = *reinterpret_cast<const short8*>(Kc + krow * 64 + ((0 + lg) ^ (krow & 7)) * 8);
      const short8 kf1 = *reinterpret_cast<const short8*>(Kc + krow * 64 + ((4 + lg) ^ (krow & 7)) * 8);
#pragma unroll
      for (int qs = 0; qs < 2; ++qs) {
        f32x4 sc = {};
        sc = __builtin_amdgcn_mfma_f32_16x16x32_bf16(qf[qs][0], kf0, sc, 0, 0, 0);
        sc = __builtin_amdgcn_mfma_f32_16x16x32_bf16(qf[qs][1], kf1, sc, 0, 0, 0);
#pragma unroll
        for (int r = 0; r < 4; ++r) {
          union { float f; unsigned u; } cv;
          cv.f = __builtin_amdgcn_exp2f(sc[r]);
          cv.u &= msel[qs][r][n];
          p[qs][n][r] = cv.f;
        }
      }
    }

    // per q-set SEQUENTIALLY: pack to LDS -> read fragment -> l-sum
    short8 pf[2][2];
#pragma unroll
    for (int qs = 0; qs < 2; ++qs) {
#pragma unroll
      for (int r = 0; r < 4; ++r) {
        const int row = lg * 4 + r;
#pragma unroll
        for (int n = 0; n < 4; ++n) {
          union { float f; unsigned u; } cv; cv.f = p[qs][n][r];
          const int col = n * 16 + lr;
          pw[row * 64 + ((col >> 3) ^ (row & 7)) * 8 + (col & 7)] = (unsigned short)(cv.u >> 16);
        }
      }
      pf[qs][0] = *reinterpret_cast<const short8*>(pw + lr * 64 + ((0 + lg) ^ (lr & 7)) * 8);
      pf[qs][1] = *reinterpret_cast<const short8*>(pw + lr * 64 + ((4 + lg) ^ (lr & 7)) * 8);
      acc_l[qs] = __builtin_amdgcn_mfma_f32_16x16x32_bf16(pf[qs][0], ones, acc_l[qs], 0, 0, 0);
      acc_l[qs] = __builtin_amdgcn_mfma_f32_16x16x32_bf16(pf[qs][1], ones, acc_l[qs], 0, 0, 0);
    }

    // O += P V
    __builtin_amdgcn_s_setprio(1);
#pragma unroll
    for (int d = 0; d < 4; ++d) {
      const int vrow = d * 16 + lr;
      const short8 vf0 = *reinterpret_cast<const short8*>(Vc + vrow * 64 + ((0 + lg) ^ (vrow & 7)) * 8);
      const short8 vf1 = *reinterpret_cast<const short8*>(Vc + vrow * 64 + ((4 + lg) ^ (vrow & 7)) * 8);
#pragma unroll
      for (int qs = 0; qs < 2; ++qs) {
        acc_o[qs][d] = __builtin_amdgcn_mfma_f32_16x16x32_bf16(pf[qs][0], vf0, acc_o[qs][d], 0, 0, 0);
        acc_o[qs][d] = __builtin_amdgcn_mfma_f32_16x16x32_bf16(pf[qs][1], vf1, acc_o[qs][d], 0, 0, 0);
      }
    }
    __builtin_amdgcn_s_setprio(0);

    // stage(t+1) complete once at most the 4 stage(t+2) loads remain in flight
    asm volatile("s_waitcnt vmcnt(4)");
    __builtin_amdgcn_s_barrier();
    __builtin_amdgcn_sched_barrier(0);
    cur = (cur == 2) ? 0 : cur + 1;
  }

#pragma unroll
  for (int qs = 0; qs < 2; ++qs)
#pragma unroll
    for (int r = 0; r < 4; ++r) {
      const float inv = __builtin_amdgcn_rcpf(acc_l[qs][r]);
      const int qrow = qbase + qs * 16 + lg * 4 + r;
      unsigned short* orow = ao + ((size_t)b * S_ + qrow) * H_ + h * HD_;
#pragma unroll
      for (int d = 0; d < 4; ++d)
        orow[d * 16 + lr] = f2bf(acc_o[qs][d][r] * inv);
    }
}

extern "C" void kernel_launch(void* const* d_in, const int* in_sizes, int n_in,
                              void* d_out, int out_size, void* d_ws, size_t ws_size,
                              hipStream_t stream) {
  (void)in_sizes; (void)n_in; (void)out_size; (void)ws_size;
  const float* query = (const float*)d_in[0];
  const float* key_  = (const float*)d_in[1];
  const float* value = (const float*)d_in[2];
  const float* mask  = (const float*)d_in[3];
  const float* Wq = (const float*)d_in[4];
  const float* bq = (const float*)d_in[5];
  const float* Wk = (const float*)d_in[6];
  const float* bk = (const float*)d_in[7];
  const float* Wv = (const float*)d_in[8];
  const float* bv = (const float*)d_in[9];
  const float* Wo = (const float*)d_in[10];
  const float* bo = (const float*)d_in[11];
  float* out = (float*)d_out;

  char* ws = (char*)d_ws;
  const size_t MB16 = (size_t)1 << 24;
  unsigned short* XQ = (unsigned short*)(ws + 0 * MB16);
  unsigned short* XK = (unsigned short*)(ws + 1 * MB16);
  unsigned short* XV = (unsigned short*)(ws + 2 * MB16);
  unsigned short* QH = (unsigned short*)(ws + 3 * MB16);
  unsigned short* KH = (unsigned short*)(ws + 4 * MB16);
  unsigned short* VH = (unsigned short*)(ws + 5 * MB16);
  unsigned short* WT = (unsigned short*)(ws + 6 * MB16);                  // 8 MB
  unsigned long long* MBits = (unsigned long long*)(ws + 6 * MB16 + (size_t)4 * H_ * H_ * 2);  // 2 MB
  unsigned short* AO = XQ;  // reuse: XQ dead after gemm_qkv
  unsigned short* VT = XK;  // reuse: XK dead after gemm_qkv

  cvt_in<<<dim3(4096, 1, 3), 256, 0, stream>>>(query, key_, value, XQ, XK, XV);
  packmask<<<dim3(2048), 256, 0, stream>>>(mask, MBits);
  cvt_w<<<dim3(16, 16, 4), 256, 0, stream>>>(Wq, Wk, Wv, Wo, WT);
  gemm_qkv<<<dim3(64, 8, 3), 256, 0, stream>>>(XQ, XK, XV, WT, bq, bk, bv, QH, KH, VH);
  vtrans<<<dim3(32, 64), 256, 0, stream>>>(VH, VT);
  attn_kernel<<<dim3(1024), 256, 0, stream>>>(QH, KH, VT, MBits, AO);
  gemm_out<<<dim3(64, 8, 1), 256, 0, stream>>>(AO, WT + 3 * (size_t)H_ * H_, bo, out);
}

// Round 10
// 257.030 us; speedup vs baseline: 1.0410x; 1.0410x over previous
//
#include <hip/hip_runtime.h>
#include <hip/hip_bf16.h>
#include <stdint.h>

#define B_ 4
#define S_ 2048
#define H_ 1024
#define NH_ 16
#define HD_ 64

typedef __attribute__((ext_vector_type(8))) short short8;
typedef __attribute__((ext_vector_type(4))) float f32x4;
typedef __attribute__((ext_vector_type(4))) unsigned short ushort4v;

__device__ __forceinline__ unsigned short f2bf(float f) {
  union { float f; unsigned u; } x; x.f = f;
  unsigned r = x.u + 0x7fffu + ((x.u >> 16) & 1u);
  return (unsigned short)(r >> 16);
}

#define ALDS16(g, l) \
  __builtin_amdgcn_global_load_lds((const __attribute__((address_space(1))) void*)(g), \
                                   (__attribute__((address_space(3))) void*)(l), 16, 0, 0)

// ---------------- input fp32 -> bf16 convert ----------------
__global__ __launch_bounds__(256) void cvt_in(
    const float* __restrict__ q, const float* __restrict__ k, const float* __restrict__ v,
    unsigned short* __restrict__ oq, unsigned short* __restrict__ ok2, unsigned short* __restrict__ ov) {
  const int z = blockIdx.z;
  const float* src = z == 0 ? q : (z == 1 ? k : v);
  unsigned short* dst = z == 0 ? oq : (z == 1 ? ok2 : ov);
  const size_t i = ((size_t)blockIdx.x * 256 + threadIdx.x) * 8;
  const f32x4 a = *reinterpret_cast<const f32x4*>(src + i);
  const f32x4 c = *reinterpret_cast<const f32x4*>(src + i + 4);
  short8 o;
#pragma unroll
  for (int j = 0; j < 4; ++j) { o[j] = (short)f2bf(a[j]); o[j + 4] = (short)f2bf(c[j]); }
  *reinterpret_cast<short8*>(dst + i) = o;
}

// ---------------- mask fp32 -> bit pack (bit set = KEEP, i.e. mask==0) ----------------
__global__ __launch_bounds__(256) void packmask(
    const float* __restrict__ mask, unsigned long long* __restrict__ mb) {
  const int w = threadIdx.x >> 6, lane = threadIdx.x & 63;
  const int wbase = (blockIdx.x * 4 + w) * 32;
#pragma unroll 8
  for (int i = 0; i < 32; ++i) {
    const float v = mask[(size_t)(wbase + i) * 64 + lane];
    const unsigned long long bits = __ballot(v == 0.0f);
    if (lane == 0) mb[wbase + i] = bits;
  }
}

// ---------------- weight fp32 -> bf16 transpose (Wt[n][k] = W[k][n]) ----------------
__global__ __launch_bounds__(256) void cvt_w(
    const float* __restrict__ Wq, const float* __restrict__ Wk,
    const float* __restrict__ Wv, const float* __restrict__ Wo,
    unsigned short* __restrict__ wt) {
  __shared__ float tile[64][65];
  const int z = blockIdx.z;
  const float* W = z == 0 ? Wq : (z == 1 ? Wk : (z == 2 ? Wv : Wo));
  unsigned short* out = wt + (size_t)z * H_ * H_;
  const int t = threadIdx.x;
  const int r0 = blockIdx.y * 64, c0 = blockIdx.x * 64;
  const int tr = t >> 4, tc = (t & 15) * 4;
#pragma unroll
  for (int rr = 0; rr < 4; ++rr) {
    const int row = rr * 16 + tr;
    const f32x4 val = *reinterpret_cast<const f32x4*>(W + (size_t)(r0 + row) * H_ + c0 + tc);
#pragma unroll
    for (int j = 0; j < 4; ++j) tile[row][tc + j] = val[j];
  }
  __syncthreads();
#pragma unroll
  for (int rr = 0; rr < 4; ++rr) {
    const int c = rr * 16 + tr;
    ushort4v o;
#pragma unroll
    for (int j = 0; j < 4; ++j) o[j] = f2bf(tile[tc + j][c]);
    *reinterpret_cast<ushort4v*>(out + (size_t)(c0 + c) * H_ + r0 + tc) = o;
  }
}

// ---------------- GEMM: C[M,1024] = (X @ Wt^T + bias) * oscale ----------------
// OUTMODE 0: bf16 head-split [B,NH,S,HD].  1: fp32 flat [M,H].  2: bf16 V-transposed [B*NH,HD,S].
template <int OUTMODE>
__device__ __forceinline__ void gemm_body(
    const unsigned short* __restrict__ X, const unsigned short* __restrict__ Wt,
    const float* __restrict__ bias, float oscale, unsigned short* __restrict__ obf,
    float* __restrict__ of32) {
  __shared__ unsigned short As[128 * 64];
  __shared__ unsigned short Bs[128 * 64];
  const int t = threadIdx.x;
  const int w = t >> 6, l = t & 63;
  const int lr = l & 15, lg = l >> 4;
  const int brow = blockIdx.x * 128, bcol = blockIdx.y * 128;
  const int wr = (w >> 1) * 64, wc = (w & 1) * 64;
  f32x4 acc[4][4] = {};
  const unsigned short* xb = X + (size_t)brow * 1024;
  const unsigned short* wb = Wt + (size_t)bcol * 1024;
  int srow[4], skl[4];
#pragma unroll
  for (int j = 0; j < 4; ++j) {
    const int c = t + j * 256;
    srow[j] = c >> 3;
    skl[j] = ((c & 7) ^ ((c >> 3) & 7)) * 8;
  }
  for (int kt = 0; kt < 1024; kt += 64) {
#pragma unroll
    for (int j = 0; j < 4; ++j) {
      ALDS16(xb + (size_t)srow[j] * 1024 + kt + skl[j], As + (t + j * 256) * 8);
      ALDS16(wb + (size_t)srow[j] * 1024 + kt + skl[j], Bs + (t + j * 256) * 8);
    }
    __syncthreads();
#pragma unroll
    for (int kk = 0; kk < 2; ++kk) {
      short8 af[4], bf[4];
#pragma unroll
      for (int m = 0; m < 4; ++m) {
        const int ra = wr + m * 16 + lr;
        af[m] = *reinterpret_cast<const short8*>(As + ra * 64 + ((kk * 4 + lg) ^ (ra & 7)) * 8);
      }
#pragma unroll
      for (int n = 0; n < 4; ++n) {
        const int rb = wc + n * 16 + lr;
        bf[n] = *reinterpret_cast<const short8*>(Bs + rb * 64 + ((kk * 4 + lg) ^ (rb & 7)) * 8);
      }
#pragma unroll
      for (int m = 0; m < 4; ++m)
#pragma unroll
        for (int n = 0; n < 4; ++n)
          acc[m][n] = __builtin_amdgcn_mfma_f32_16x16x32_bf16(af[m], bf[n], acc[m][n], 0, 0, 0);
    }
    __syncthreads();
  }
#pragma unroll
  for (int m = 0; m < 4; ++m) {
#pragma unroll
    for (int n = 0; n < 4; ++n) {
      const int gr0 = brow + wr + m * 16 + lg * 4;
      const int gc = bcol + wc + n * 16 + lr;
      if (OUTMODE == 2) {
        // V-transposed: 4 consecutive s-rows at fixed (hh,dd) -> contiguous store
        ushort4v o;
#pragma unroll
        for (int r = 0; r < 4; ++r) o[r] = f2bf((acc[m][n][r] + bias[gc]) * oscale);
        const int bb = gr0 >> 11, ss = gr0 & 2047, hh = gc >> 6, dd = gc & 63;
        *reinterpret_cast<ushort4v*>(obf + ((size_t)(bb * NH_ + hh) * HD_ + dd) * S_ + ss) = o;
      } else {
#pragma unroll
        for (int r = 0; r < 4; ++r) {
          const int gr = gr0 + r;
          const float val = (acc[m][n][r] + bias[gc]) * oscale;
          if (OUTMODE == 0) {
            const int bb = gr >> 11, ss = gr & 2047, hh = gc >> 6, dd = gc & 63;
            obf[(((size_t)(bb * NH_ + hh)) * S_ + ss) * HD_ + dd] = f2bf(val);
          } else {
            of32[(size_t)gr * H_ + gc] = val;
          }
        }
      }
    }
  }
}

// Q is pre-scaled by 0.125*log2(e) so attention can exp2() the raw MFMA output.
#define QSCL 0.1803368801111244f

__global__ __launch_bounds__(256, 4) void gemm_qkv(
    const unsigned short* __restrict__ xq, const unsigned short* __restrict__ xk,
    const unsigned short* __restrict__ wt,
    const float* __restrict__ bq, const float* __restrict__ bk,
    unsigned short* __restrict__ qh, unsigned short* __restrict__ kh) {
  const int z = blockIdx.z;
  const unsigned short* X = z == 0 ? xq : xk;
  const unsigned short* W = wt + (size_t)z * H_ * H_;
  const float* bias = z == 0 ? bq : bk;
  unsigned short* out = z == 0 ? qh : kh;
  const float scl = z == 0 ? QSCL : 1.0f;
  gemm_body<0>(X, W, bias, scl, out, nullptr);
}

__global__ __launch_bounds__(256, 4) void gemm_v(
    const unsigned short* __restrict__ xv, const unsigned short* __restrict__ wt,
    const float* __restrict__ bv, unsigned short* __restrict__ vtv) {
  gemm_body<2>(xv, wt + (size_t)2 * H_ * H_, bv, 1.0f, vtv, nullptr);
}

__global__ __launch_bounds__(256, 4) void gemm_out(
    const unsigned short* __restrict__ ao, const unsigned short* __restrict__ wt,
    const float* __restrict__ bo, float* __restrict__ out) {
  gemm_body<1>(ao, wt, bo, 1.0f, nullptr, out);
}

// ---------------- flash attention ----------------
// 2048 blocks x 64 q-rows (4 waves x 16 rows, 1 q-set/wave). LDS 40 KB ->
// 4 blocks/CU -> 4 waves/SIMD (2x TLP vs r7-r9). Residency: 128 resident
// blocks/XCD = 4 heads x 32 q-tiles = 2 MB K/V per L2 (r7-proven budget).
// Map: xcd=id&7, gen=id>>10, hh=(id>>8)&3, qt=(id>>3)&31.
__global__ __launch_bounds__(256, 4) void attn_kernel(
    const unsigned short* __restrict__ qh, const unsigned short* __restrict__ kh,
    const unsigned short* __restrict__ vt, const unsigned long long* __restrict__ mb,
    unsigned short* __restrict__ ao) {
  __shared__ unsigned short Ks[2][64 * 64];
  __shared__ unsigned short Vs[2][64 * 64];
  __shared__ unsigned short Ps[4][16 * 64];
  const int t = threadIdx.x, w = t >> 6, l = t & 63;
  const int lr = l & 15, lg = l >> 4;
  const int flat = blockIdx.x;
  const int xcd = flat & 7;
  const int gen = flat >> 10;
  const int hh = (flat >> 8) & 3;
  const int qt = (flat >> 3) & 31;
  const int bh = gen * 32 + xcd * 4 + hh;
  const int b = bh >> 4, h = bh & 15;
  const unsigned short* qptr = qh + (size_t)bh * S_ * HD_;
  const unsigned short* kptr = kh + (size_t)bh * S_ * HD_;
  const unsigned short* vptr = vt + (size_t)bh * HD_ * S_;
  const unsigned long long* mbase = mb + (size_t)b * S_ * (S_ / 64);
  const int qbase = qt * 64 + w * 16;

  short8 qf[2];
  {
    const unsigned short* qp = qptr + (size_t)(qbase + lr) * HD_ + lg * 8;
    qf[0] = *reinterpret_cast<const short8*>(qp);
    qf[1] = *reinterpret_cast<const short8*>(qp + 32);
  }
  short8 ones;
#pragma unroll
  for (int jj = 0; jj < 8; ++jj) ones[jj] = (short)0x3F80;

  const int si0 = t, si1 = t + 256;
  const int srow0 = si0 >> 3, sk0 = ((si0 & 7) ^ (srow0 & 7)) * 8;
  const int srow1 = si1 >> 3, sk1 = ((si1 & 7) ^ (srow1 & 7)) * 8;
  const unsigned short* ksrc0 = kptr + (size_t)srow0 * HD_ + sk0;
  const unsigned short* ksrc1 = kptr + (size_t)srow1 * HD_ + sk1;
  const unsigned short* vsrc0 = vptr + (size_t)srow0 * S_ + sk0;
  const unsigned short* vsrc1 = vptr + (size_t)srow1 * S_ + sk1;
  size_t moff[4];
#pragma unroll
  for (int r = 0; r < 4; ++r)
    moff[r] = (size_t)(qbase + lg * 4 + r) * (S_ / 64);

  // prologue: stage tile 0 into buffer 0
  ALDS16(ksrc0, Ks[0] + si0 * 8);
  ALDS16(ksrc1, Ks[0] + si1 * 8);
  ALDS16(vsrc0, Vs[0] + si0 * 8);
  ALDS16(vsrc1, Vs[0] + si1 * 8);
  __syncthreads();

  f32x4 acc_o[4] = {};
  f32x4 acc_l = {};
  unsigned short* pw = Ps[w];
  int cur = 0;

  for (int kv = 0; kv < S_; kv += 64) {
    // mask bits -> per-element AND masks
    unsigned msel[4][4];
#pragma unroll
    for (int r = 0; r < 4; ++r) {
      const unsigned long long mwv = mbase[moff[r] + (kv >> 6)];
      const unsigned long long sh = mwv >> lr;
      const unsigned lo = (unsigned)sh, hi = (unsigned)(sh >> 32);
      msel[r][0] = 0u - (lo & 1u);
      msel[r][1] = 0u - ((lo >> 16) & 1u);
      msel[r][2] = 0u - (hi & 1u);
      msel[r][3] = 0u - ((hi >> 16) & 1u);
    }

    // stage NEXT tile into other buffer
    const int nkv = (kv + 64 < S_) ? kv + 64 : 0;
    ALDS16(ksrc0 + (size_t)nkv * HD_, Ks[cur ^ 1] + si0 * 8);
    ALDS16(ksrc1 + (size_t)nkv * HD_, Ks[cur ^ 1] + si1 * 8);
    ALDS16(vsrc0 + nkv, Vs[cur ^ 1] + si0 * 8);
    ALDS16(vsrc1 + nkv, Vs[cur ^ 1] + si1 * 8);

    const unsigned short* Kc = Ks[cur];
    const unsigned short* Vc = Vs[cur];

    // QK^T -> exp2 -> mask
    float p[4][4];
#pragma unroll
    for (int n = 0; n < 4; ++n) {
      const int krow = n * 16 + lr;
      const short8 kf0 = *reinterpret_cast<const short8*>(Kc + krow * 64 + ((0 + lg) ^ (krow & 7)) * 8);
      const short8 kf1 = *reinterpret_cast<const short8*>(Kc + krow * 64 + ((4 + lg) ^ (krow & 7)) * 8);
      f32x4 sc = {};
      sc = __builtin_amdgcn_mfma_f32_16x16x32_bf16(qf[0], kf0, sc, 0, 0, 0);
      sc = __builtin_amdgcn_mfma_f32_16x16x32_bf16(qf[1], kf1, sc, 0, 0, 0);
#pragma unroll
      for (int r = 0; r < 4; ++r) {
        union { float f; unsigned u; } cv;
        cv.f = __builtin_amdgcn_exp2f(sc[r]);
        cv.u &= msel[r][n];
        p[n][r] = cv.f;
      }
    }

    // pack P to LDS -> read fragments -> l-sum via MFMA-ones
#pragma unroll
    for (int r = 0; r < 4; ++r) {
      const int row = lg * 4 + r;
#pragma unroll
      for (int n = 0; n < 4; ++n) {
        union { float f; unsigned u; } cv; cv.f = p[n][r];
        const int col = n * 16 + lr;
        pw[row * 64 + ((col >> 3) ^ (row & 7)) * 8 + (col & 7)] = (unsigned short)(cv.u >> 16);
      }
    }
    short8 pf0 = *reinterpret_cast<const short8*>(pw + lr * 64 + ((0 + lg) ^ (lr & 7)) * 8);
    short8 pf1 = *reinterpret_cast<const short8*>(pw + lr * 64 + ((4 + lg) ^ (lr & 7)) * 8);
    acc_l = __builtin_amdgcn_mfma_f32_16x16x32_bf16(pf0, ones, acc_l, 0, 0, 0);
    acc_l = __builtin_amdgcn_mfma_f32_16x16x32_bf16(pf1, ones, acc_l, 0, 0, 0);

    // O += P V
    __builtin_amdgcn_s_setprio(1);
#pragma unroll
    for (int d = 0; d < 4; ++d) {
      const int vrow = d * 16 + lr;
      const short8 vf0 = *reinterpret_cast<const short8*>(Vc + vrow * 64 + ((0 + lg) ^ (vrow & 7)) * 8);
      const short8 vf1 = *reinterpret_cast<const short8*>(Vc + vrow * 64 + ((4 + lg) ^ (vrow & 7)) * 8);
      acc_o[d] = __builtin_amdgcn_mfma_f32_16x16x32_bf16(pf0, vf0, acc_o[d], 0, 0, 0);
      acc_o[d] = __builtin_amdgcn_mfma_f32_16x16x32_bf16(pf1, vf1, acc_o[d], 0, 0, 0);
    }
    __builtin_amdgcn_s_setprio(0);
    __syncthreads();
    cur ^= 1;
  }

#pragma unroll
  for (int r = 0; r < 4; ++r) {
    const float inv = __builtin_amdgcn_rcpf(acc_l[r]);
    const int qrow = qbase + lg * 4 + r;
    unsigned short* orow = ao + ((size_t)b * S_ + qrow) * H_ + h * HD_;
#pragma unroll
    for (int d = 0; d < 4; ++d)
      orow[d * 16 + lr] = f2bf(acc_o[d][r] * inv);
  }
}

extern "C" void kernel_launch(void* const* d_in, const int* in_sizes, int n_in,
                              void* d_out, int out_size, void* d_ws, size_t ws_size,
                              hipStream_t stream) {
  (void)in_sizes; (void)n_in; (void)out_size; (void)ws_size;
  const float* query = (const float*)d_in[0];
  const float* key_  = (const float*)d_in[1];
  const float* value = (const float*)d_in[2];
  const float* mask  = (const float*)d_in[3];
  const float* Wq = (const float*)d_in[4];
  const float* bq = (const float*)d_in[5];
  const float* Wk = (const float*)d_in[6];
  const float* bk = (const float*)d_in[7];
  const float* Wv = (const float*)d_in[8];
  const float* bv = (const float*)d_in[9];
  const float* Wo = (const float*)d_in[10];
  const float* bo = (const float*)d_in[11];
  float* out = (float*)d_out;

  char* ws = (char*)d_ws;
  const size_t MB16 = (size_t)1 << 24;
  unsigned short* XQ = (unsigned short*)(ws + 0 * MB16);
  unsigned short* XK = (unsigned short*)(ws + 1 * MB16);
  unsigned short* XV = (unsigned short*)(ws + 2 * MB16);
  unsigned short* QH = (unsigned short*)(ws + 3 * MB16);
  unsigned short* KH = (unsigned short*)(ws + 4 * MB16);
  unsigned short* VT = (unsigned short*)(ws + 5 * MB16);  // V written transposed by gemm_v
  unsigned short* WT = (unsigned short*)(ws + 6 * MB16);  // 8 MB
  unsigned long long* MBits = (unsigned long long*)(ws + 6 * MB16 + (size_t)4 * H_ * H_ * 2);  // 2 MB
  unsigned short* AO = XQ;  // reuse: XQ dead after gemm_qkv

  cvt_in<<<dim3(4096, 1, 3), 256, 0, stream>>>(query, key_, value, XQ, XK, XV);
  packmask<<<dim3(2048), 256, 0, stream>>>(mask, MBits);
  cvt_w<<<dim3(16, 16, 4), 256, 0, stream>>>(Wq, Wk, Wv, Wo, WT);
  gemm_qkv<<<dim3(64, 8, 2), 256, 0, stream>>>(XQ, XK, WT, bq, bk, QH, KH);
  gemm_v<<<dim3(64, 8), 256, 0, stream>>>(XV, WT, bv, VT);
  attn_kernel<<<dim3(2048), 256, 0, stream>>>(QH, KH, VT, MBits, AO);
  gemm_out<<<dim3(64, 8, 1), 256, 0, stream>>>(AO, WT + 3 * (size_t)H_ * H_, bo, out);
}